// Round 4
// baseline (493.450 us; speedup 1.0000x reference)
//
#include <hip/hip_runtime.h>

typedef unsigned short u16;
typedef unsigned int   u32;
typedef unsigned long long u64;
typedef _Float16 f16;
typedef f16 f16x8 __attribute__((ext_vector_type(8)));
typedef f16 f16x4 __attribute__((ext_vector_type(4)));
typedef float f32x4 __attribute__((ext_vector_type(4)));

#define N_ROWS 50000
#define D_DIM  2048
#define H_DIM  512
#define KSEL   5000
#define SORT_N 8192

// ---------- workspace layout (bytes) ----------
#define W1F_OFF    0u          // 512*2048 f16 (2 MB)
#define PART_OFF   2097152u    // 2 x 50000 f32 (400 KB)
#define SCORES_OFF 2555904u    // 50000 f32
#define HIST_OFF   2752512u    // 65536 u32 (256 KB)
#define AKW_OFF    3014656u    // 5000 f32
#define SIDX_OFF   3047424u    // 5000 u32
#define GPART_OFF  3080192u    // 256*2048 f32 (2 MB)
#define XF_OFF     8388608u    // 50000*2048 f16 (204.8 MB)
#define WS_NEED    213188608ull

__device__ __forceinline__ u32 mono_bits(float s){
  u32 u = __float_as_uint(s);
  return (u & 0x80000000u) ? ~u : (u | 0x80000000u);
}
__device__ __forceinline__ void gload_lds16(const void* g, void* l){
  __builtin_amdgcn_global_load_lds((__attribute__((address_space(1))) void*)(void*)g,
                                   (__attribute__((address_space(3))) void*)l, 16, 0, 0);
}

// ---------- W1 -> fp16 ----------
__global__ void prep_w1_f16(const float* __restrict__ w1, f16* __restrict__ w1f){
  int i = (blockIdx.x * 256 + threadIdx.x) * 4;   // 1024*256*4 = 1048576 exact
  float4 v = *(const float4*)(w1 + i);
  f16x4 h;
  h[0] = (f16)v.x; h[1] = (f16)v.y; h[2] = (f16)v.z; h[3] = (f16)v.w;
  *(f16x4*)(w1f + i) = h;
}

// ---------- x -> fp16 (grid-stride, memory-bound) ----------
__global__ void prep_x_f16(const float* __restrict__ x, f16* __restrict__ xf){
  size_t i = ((size_t)blockIdx.x * 256 + threadIdx.x) * 8;
  const size_t stride = (size_t)gridDim.x * 256 * 8;
  const size_t total = (size_t)N_ROWS * D_DIM;
  for (; i < total; i += stride){
    float4 v0 = *(const float4*)(x + i);
    float4 v1 = *(const float4*)(x + i + 4);
    f16x8 h;
    h[0]=(f16)v0.x; h[1]=(f16)v0.y; h[2]=(f16)v0.z; h[3]=(f16)v0.w;
    h[4]=(f16)v1.x; h[5]=(f16)v1.y; h[6]=(f16)v1.z; h[7]=(f16)v1.w;
    *(f16x8*)(xf + i) = h;
  }
}

// ---------- 8-phase-style fused scores GEMM ----------
// Block 256x256, BK=64, 8 waves (2M x 4N), wave-tile 128x64. Both operands f16
// staged via global_load_lds (pre-swizzled source, linear LDS dest). Counted
// vmcnt(8): next tile's 8 DMAs stay in flight across the K-loop barrier.
// 4 compute phases per tile, setprio(1) around each 16-MFMA cluster.
__global__ __launch_bounds__(512, 2) void gemm_8ph(
    const f16* __restrict__ xf, const f16* __restrict__ w1f,
    const float* __restrict__ b1, const float* __restrict__ w2, float* __restrict__ partial)
{
  __shared__ __align__(16) f16 At[2][16384];   // 256 x 64, 32 KB per buf
  __shared__ __align__(16) f16 Bt[2][16384];

  const int t = threadIdx.x, l = t & 63, w = t >> 6;
  const int wm = w >> 2, wn = w & 3;
  int nn = (blockIdx.x & 7) * 49 + (blockIdx.x >> 3);   // bijective: 392 = 8*49
  const int bx = nn / 196, by = nn % 196;
  const int h0 = bx * 256, r0 = by * 256;

  f32x4 acc[8][4] = {};

  // staging: pass p -> row p*64 + (t>>3), 16B chunk slot (t&7); source chunk
  // pre-swizzled (slot ^ row&7) so LDS dest stays lane-linear (base + l*16B).
  const int srow = t >> 3;
  const int schunk = ((t & 7) ^ (srow & 7)) * 8;       // f16 offset in row
  const f16* asrc[4];
  #pragma unroll
  for (int p = 0; p < 4; ++p){
    int gr = r0 + p * 64 + srow; if (gr > N_ROWS - 1) gr = N_ROWS - 1;
    asrc[p] = xf + (size_t)gr * D_DIM + schunk;
  }
  const f16* bsrc = w1f + (size_t)(h0 + srow) * D_DIM + schunk;
  const int dstq = srow * 64 + (t & 7) * 8;            // f16 idx; + p*4096

  // fragment LDS indices (swizzled read side)
  int aidx[8][2], bidx[4][2];
  #pragma unroll
  for (int mt = 0; mt < 8; ++mt){
    int row = wm * 128 + mt * 16 + (l & 15);
    #pragma unroll
    for (int ks = 0; ks < 2; ++ks){
      int chunk = ks * 4 + (l >> 4);
      aidx[mt][ks] = row * 64 + ((chunk ^ (row & 7)) << 3);
    }
  }
  #pragma unroll
  for (int nt = 0; nt < 4; ++nt){
    int row = wn * 64 + nt * 16 + (l & 15);
    #pragma unroll
    for (int ks = 0; ks < 2; ++ks){
      int chunk = ks * 4 + (l >> 4);
      bidx[nt][ks] = row * 64 + ((chunk ^ (row & 7)) << 3);
    }
  }

  // prologue: stage tile 0 -> buf 0
  #pragma unroll
  for (int p = 0; p < 4; ++p)
    gload_lds16(bsrc + (size_t)p * 64 * D_DIM, &Bt[0][p * 4096 + dstq]);
  #pragma unroll
  for (int p = 0; p < 4; ++p)
    gload_lds16(asrc[p], &At[0][p * 4096 + dstq]);

  for (int kt = 0; kt < 32; ++kt){
    const int cur = kt & 1;
    const f16* Ab = At[cur];
    const f16* Bb = Bt[cur];

    // stage tile kt+1 into buf cur^1 (WAR-safe: that buffer's readers were
    // barrier-retired at the end of iter kt-1), then counted wait for tile kt.
    if (kt + 1 < 32){
      const int k0 = (kt + 1) * 64;
      #pragma unroll
      for (int p = 0; p < 4; ++p)
        gload_lds16(bsrc + (size_t)p * 64 * D_DIM + k0, &Bt[cur ^ 1][p * 4096 + dstq]);
      #pragma unroll
      for (int p = 0; p < 4; ++p)
        gload_lds16(asrc[p] + k0, &At[cur ^ 1][p * 4096 + dstq]);
      asm volatile("s_waitcnt vmcnt(8)" ::: "memory");
    } else {
      asm volatile("s_waitcnt vmcnt(0)" ::: "memory");
    }
    __builtin_amdgcn_sched_barrier(0);
    __builtin_amdgcn_s_barrier();            // tile kt visible to all waves
    __builtin_amdgcn_sched_barrier(0);

    // phase 0 preload: all B-frags for this tile
    f16x8 bfr[4][2];
    #pragma unroll
    for (int nt = 0; nt < 4; ++nt)
      #pragma unroll
      for (int ks = 0; ks < 2; ++ks)
        bfr[nt][ks] = *(const f16x8*)&Bb[bidx[nt][ks]];

#define PHASE(m0, m1) { \
    f16x8 a00 = *(const f16x8*)&Ab[aidx[m0][0]]; \
    f16x8 a01 = *(const f16x8*)&Ab[aidx[m0][1]]; \
    f16x8 a10 = *(const f16x8*)&Ab[aidx[m1][0]]; \
    f16x8 a11 = *(const f16x8*)&Ab[aidx[m1][1]]; \
    __builtin_amdgcn_s_setprio(1); \
    _Pragma("unroll") \
    for (int nt = 0; nt < 4; ++nt){ \
      acc[m0][nt] = __builtin_amdgcn_mfma_f32_16x16x32_f16(a00, bfr[nt][0], acc[m0][nt], 0, 0, 0); \
      acc[m0][nt] = __builtin_amdgcn_mfma_f32_16x16x32_f16(a01, bfr[nt][1], acc[m0][nt], 0, 0, 0); \
      acc[m1][nt] = __builtin_amdgcn_mfma_f32_16x16x32_f16(a10, bfr[nt][0], acc[m1][nt], 0, 0, 0); \
      acc[m1][nt] = __builtin_amdgcn_mfma_f32_16x16x32_f16(a11, bfr[nt][1], acc[m1][nt], 0, 0, 0); \
    } \
    __builtin_amdgcn_s_setprio(0); \
    asm volatile("s_waitcnt lgkmcnt(0)" ::: "memory"); \
    __builtin_amdgcn_sched_barrier(0); \
    __builtin_amdgcn_s_barrier(); \
    __builtin_amdgcn_sched_barrier(0); }

    PHASE(0, 1)
    PHASE(2, 3)
    PHASE(4, 5)
    PHASE(6, 7)
#undef PHASE
  }

  // ---- epilogue: tanh(z+b1)*w2, reduce over block's 256 cols ----
  // acc[mt][nt] reg j: row = wm*128 + mt*16 + (l>>4)*4 + j, col = wn*64 + nt*16 + (l&15)
  float (*EPI)[4] = (float(*)[4])At;   // alias: K-loop done, waves aligned at last barrier
  #pragma unroll
  for (int mt = 0; mt < 8; ++mt){
    float rsum[4] = {0.f, 0.f, 0.f, 0.f};
    #pragma unroll
    for (int nt = 0; nt < 4; ++nt){
      int h = h0 + wn * 64 + nt * 16 + (l & 15);
      float w2v = w2[h], b1v = b1[h];
      #pragma unroll
      for (int j = 0; j < 4; ++j)
        rsum[j] += tanhf(acc[mt][nt][j] + b1v) * w2v;
    }
    #pragma unroll
    for (int off = 1; off < 16; off <<= 1)
      #pragma unroll
      for (int j = 0; j < 4; ++j) rsum[j] += __shfl_xor(rsum[j], off, 64);
    if ((l & 15) == 0){
      int g = l >> 4;
      #pragma unroll
      for (int j = 0; j < 4; ++j) EPI[wm * 128 + mt * 16 + g * 4 + j][wn] = rsum[j];
    }
  }
  __syncthreads();
  if (t < 256){
    int n = r0 + t;
    if (n < N_ROWS)
      partial[(size_t)bx * N_ROWS + n] = EPI[t][0] + EPI[t][1] + EPI[t][2] + EPI[t][3];
  }
}

// ---------- fallback GEMM (R3 structure, used only if ws too small) ----------
__global__ __launch_bounds__(512, 2) void gemm_fb(
    const float* __restrict__ x, const f16* __restrict__ w1f,
    const float* __restrict__ b1, const float* __restrict__ w2, float* __restrict__ partial)
{
  __shared__ __align__(16) f16 At[2][16384];
  __shared__ __align__(16) f16 Bt[2][16384];
  const int t = threadIdx.x, l = t & 63, w = t >> 6;
  const int wm = w >> 2, wn = w & 3;
  int nn = (blockIdx.x & 7) * 49 + (blockIdx.x >> 3);
  const int bx = nn / 196, by = nn % 196;
  const int h0 = bx * 256, r0 = by * 256;
  f32x4 acc[8][4] = {};
  const int srow = t >> 3;
  const f16* wsrc = w1f + (size_t)(h0 + srow) * D_DIM + ((t & 7) ^ (srow & 7)) * 8;
  const int wdst = srow * 64 + (t & 7) * 8;
  const int xrow_l = t >> 3, xc = t & 7;
  const float* xptr[4];
  #pragma unroll
  for (int p = 0; p < 4; ++p){
    int gr = r0 + p * 64 + xrow_l; if (gr > N_ROWS - 1) gr = N_ROWS - 1;
    xptr[p] = x + (size_t)gr * D_DIM + xc * 8;
  }
  const int xdst = xrow_l * 64 + ((xc ^ (xrow_l & 7)) << 3);
  {
    #pragma unroll
    for (int p = 0; p < 4; ++p)
      gload_lds16(wsrc + (size_t)p * 64 * D_DIM, &Bt[0][p * 4096 + wdst]);
    #pragma unroll
    for (int p = 0; p < 4; ++p){
      float4 v0 = *(const float4*)(xptr[p]);
      float4 v1 = *(const float4*)(xptr[p] + 4);
      f16x8 v;
      v[0]=(f16)v0.x; v[1]=(f16)v0.y; v[2]=(f16)v0.z; v[3]=(f16)v0.w;
      v[4]=(f16)v1.x; v[5]=(f16)v1.y; v[6]=(f16)v1.z; v[7]=(f16)v1.w;
      *(f16x8*)&At[0][p * 4096 + xdst] = v;
    }
  }
  __syncthreads();
  int buf = 0;
  for (int kt = 0; kt < 32; ++kt){
    const int k0n = (kt + 1) * 64;
    float4 xr[4][2];
    if (kt < 31){
      #pragma unroll
      for (int p = 0; p < 4; ++p){
        xr[p][0] = *(const float4*)(xptr[p] + k0n);
        xr[p][1] = *(const float4*)(xptr[p] + k0n + 4);
      }
      #pragma unroll
      for (int p = 0; p < 4; ++p)
        gload_lds16(wsrc + (size_t)p * 64 * D_DIM + k0n, &Bt[buf ^ 1][p * 4096 + wdst]);
    }
    #pragma unroll
    for (int ks = 0; ks < 2; ++ks){
      const int chunk = ks * 4 + (l >> 4);
      f16x8 bfr[4];
      #pragma unroll
      for (int nt = 0; nt < 4; ++nt){
        int row = wn * 64 + nt * 16 + (l & 15);
        bfr[nt] = *(const f16x8*)&Bt[buf][row * 64 + ((chunk ^ (row & 7)) << 3)];
      }
      #pragma unroll
      for (int mt = 0; mt < 8; ++mt){
        int row = wm * 128 + mt * 16 + (l & 15);
        f16x8 af = *(const f16x8*)&At[buf][row * 64 + ((chunk ^ (row & 7)) << 3)];
        #pragma unroll
        for (int nt = 0; nt < 4; ++nt)
          acc[mt][nt] = __builtin_amdgcn_mfma_f32_16x16x32_f16(af, bfr[nt], acc[mt][nt], 0, 0, 0);
      }
    }
    if (kt < 31){
      #pragma unroll
      for (int p = 0; p < 4; ++p){
        f16x8 v;
        v[0]=(f16)xr[p][0].x; v[1]=(f16)xr[p][0].y; v[2]=(f16)xr[p][0].z; v[3]=(f16)xr[p][0].w;
        v[4]=(f16)xr[p][1].x; v[5]=(f16)xr[p][1].y; v[6]=(f16)xr[p][1].z; v[7]=(f16)xr[p][1].w;
        *(f16x8*)&At[buf ^ 1][p * 4096 + xdst] = v;
      }
    }
    __syncthreads();
    buf ^= 1;
  }
  float (*EPI)[4] = (float(*)[4])At;
  #pragma unroll
  for (int mt = 0; mt < 8; ++mt){
    float rsum[4] = {0.f, 0.f, 0.f, 0.f};
    #pragma unroll
    for (int nt = 0; nt < 4; ++nt){
      int h = h0 + wn * 64 + nt * 16 + (l & 15);
      float w2v = w2[h], b1v = b1[h];
      #pragma unroll
      for (int j = 0; j < 4; ++j)
        rsum[j] += tanhf(acc[mt][nt][j] + b1v) * w2v;
    }
    #pragma unroll
    for (int off = 1; off < 16; off <<= 1)
      #pragma unroll
      for (int j = 0; j < 4; ++j) rsum[j] += __shfl_xor(rsum[j], off, 64);
    if ((l & 15) == 0){
      int g = l >> 4;
      #pragma unroll
      for (int j = 0; j < 4; ++j) EPI[wm * 128 + mt * 16 + g * 4 + j][wn] = rsum[j];
    }
  }
  __syncthreads();
  if (t < 256){
    int n = r0 + t;
    if (n < N_ROWS)
      partial[(size_t)bx * N_ROWS + n] = EPI[t][0] + EPI[t][1] + EPI[t][2] + EPI[t][3];
  }
}

// ---------- score reduce + 16-bit-bin histogram ----------
__global__ void reduce_hist(const float* __restrict__ partial, float* __restrict__ scores,
                            u32* __restrict__ hist){
  int n = blockIdx.x * 256 + threadIdx.x;
  if (n >= N_ROWS) return;
  float s = partial[n] + partial[N_ROWS + n];     // b2 omitted: cancels in softmax/top-k
  scores[n] = s;
  atomicAdd(&hist[mono_bits(s) >> 16], 1u);
}

// ---------- fused: threshold scan + compact + bitonic sort + softmax ----------
__global__ __launch_bounds__(1024) void topk_fused(
    const u32* __restrict__ hist, const float* __restrict__ scores,
    float* __restrict__ akw, u32* __restrict__ sidx, float* __restrict__ out)
{
  __shared__ u64 KEY[SORT_N];        // 64 KB
  __shared__ u32 csum[1024];
  __shared__ float red[1024];
  __shared__ int sh_c, sh_T, sh_cnt;
  const int t = threadIdx.x;

  u32 s = 0;
  for (int i = 0; i < 64; ++i) s += hist[t * 64 + i];
  csum[t] = s;
  __syncthreads();
  for (int off = 1; off < 1024; off <<= 1){
    u32 v = (t + off < 1024) ? csum[t + off] : 0u;
    __syncthreads();
    csum[t] += v;
    __syncthreads();
  }
  if (csum[t] >= (u32)KSEL && (t == 1023 || csum[t + 1] < (u32)KSEL)) sh_c = t;
  __syncthreads();
  if (t == 0){
    int c = sh_c;
    u32 cnt = (c < 1023) ? csum[c + 1] : 0u;
    int T = c * 64;
    for (int b = c * 64 + 63; b >= c * 64; --b){
      cnt += hist[b];
      if (cnt >= (u32)KSEL){ T = b; break; }
    }
    sh_T = T; sh_cnt = 0;
  }
  __syncthreads();

  const int T = sh_T;
  for (int n = t; n < N_ROWS; n += 1024){
    u32 u = mono_bits(scores[n]);
    if ((int)(u >> 16) >= T){
      int p = atomicAdd(&sh_cnt, 1);
      if (p < SORT_N) KEY[p] = ((u64)u << 32) | (u32)(~n);   // value desc, idx asc
    }
  }
  __syncthreads();
  int C = sh_cnt; if (C > SORT_N) C = SORT_N;
  for (int i = t; i < SORT_N; i += 1024) if (i >= C) KEY[i] = 0ull;
  __syncthreads();

  for (int size = 2; size <= SORT_N; size <<= 1){
    for (int stride = size >> 1; stride > 0; stride >>= 1){
      for (int q = 0; q < SORT_N; q += 1024){
        int i = q + t, j = i ^ stride;
        if (j > i){
          u64 a = KEY[i], b = KEY[j];
          bool desc = ((i & size) == 0);
          if (desc ? (a < b) : (a > b)){ KEY[i] = b; KEY[j] = a; }
        }
      }
      __syncthreads();
    }
  }

  u32 id0 = ~(u32)(KEY[0] & 0xFFFFFFFFull);
  float m = scores[id0];
  float ev[5]; u32 id[5];
  float local = 0.f;
  #pragma unroll
  for (int r = 0; r < 5; ++r){
    int j = t + r * 1024;
    if (j < KSEL){
      id[r] = ~(u32)(KEY[j] & 0xFFFFFFFFull);
      ev[r] = expf(scores[id[r]] - m);
      local += ev[r];
    }
  }
  red[t] = local;
  __syncthreads();
  for (int o = 512; o > 0; o >>= 1){ if (t < o) red[t] += red[t + o]; __syncthreads(); }
  float S = red[0];
  #pragma unroll
  for (int r = 0; r < 5; ++r){
    int j = t + r * 1024;
    if (j < KSEL){
      float a = ev[r] / S;
      akw[j] = a; sidx[j] = id[r]; out[D_DIM + j] = a;
    }
  }
}

// ---------- gather + weighted sum (deterministic 2-pass) ----------
__global__ void gather_M(const float* __restrict__ x, const u32* __restrict__ sidx,
                         const float* __restrict__ akw, float* __restrict__ gpart){
  int t = threadIdx.x, b = blockIdx.x;   // 256 blocks
  float a8[8] = {0.f,0.f,0.f,0.f,0.f,0.f,0.f,0.f};
  for (int j = b; j < KSEL; j += 256){
    float a = akw[j];
    const float* xr = x + (size_t)sidx[j] * D_DIM;
    #pragma unroll
    for (int c = 0; c < 8; ++c) a8[c] += a * xr[t + c * 256];
  }
  #pragma unroll
  for (int c = 0; c < 8; ++c) gpart[(size_t)b * D_DIM + t + c * 256] = a8[c];
}
__global__ void reduce_M(const float* __restrict__ gpart, float* __restrict__ out){
  int d = blockIdx.x * 256 + threadIdx.x;
  float s = 0.f;
  for (int b = 0; b < 256; ++b) s += gpart[(size_t)b * D_DIM + d];
  out[d] = s;
}

extern "C" void kernel_launch(void* const* d_in, const int* in_sizes, int n_in,
                              void* d_out, int out_size, void* d_ws, size_t ws_size,
                              hipStream_t stream) {
  const float* x  = (const float*)d_in[0];
  const float* W1 = (const float*)d_in[1];
  const float* b1 = (const float*)d_in[2];
  const float* W2 = (const float*)d_in[3];
  // b2 (d_in[4]) cancels in softmax/top-k -> unused
  float* out = (float*)d_out;
  char* ws = (char*)d_ws;

  f16* w1f     = (f16*)(ws + W1F_OFF);
  float* part  = (float*)(ws + PART_OFF);
  float* scr   = (float*)(ws + SCORES_OFF);
  u32* hist    = (u32*)(ws + HIST_OFF);
  float* akw   = (float*)(ws + AKW_OFF);
  u32* sidx    = (u32*)(ws + SIDX_OFF);
  float* gpart = (float*)(ws + GPART_OFF);
  f16* xf      = (f16*)(ws + XF_OFF);

  (void)in_sizes; (void)n_in; (void)out_size;

  hipMemsetAsync(ws + HIST_OFF, 0, 262144, stream);
  prep_w1_f16<<<1024, 256, 0, stream>>>(W1, w1f);
  if (ws_size >= WS_NEED){
    prep_x_f16<<<2048, 256, 0, stream>>>(x, xf);
    gemm_8ph<<<392, 512, 0, stream>>>(xf, w1f, b1, W2, part);
  } else {
    gemm_fb<<<392, 512, 0, stream>>>(x, w1f, b1, W2, part);
  }
  reduce_hist<<<196, 256, 0, stream>>>(part, scr, hist);
  topk_fused<<<1, 1024, 0, stream>>>(hist, scr, akw, sidx, out);
  gather_M<<<256, 256, 0, stream>>>(x, sidx, akw, gpart);
  reduce_M<<<8, 256, 0, stream>>>(gpart, out);
}

// Round 5
// 474.908 us; speedup vs baseline: 1.0390x; 1.0390x over previous
//
#include <hip/hip_runtime.h>

typedef unsigned short u16;
typedef unsigned int   u32;
typedef unsigned long long u64;
typedef _Float16 f16;
typedef f16 f16x8 __attribute__((ext_vector_type(8)));
typedef f16 f16x4 __attribute__((ext_vector_type(4)));
typedef float f32x4 __attribute__((ext_vector_type(4)));

#define N_ROWS 50000
#define D_DIM  2048
#define H_DIM  512
#define KSEL   5000
#define NBIN   65536
#define CAND_MAX 50176   // keys slots (196*256)

// ---------- workspace layout (bytes) ----------
#define W1F_OFF    0u          // 512*2048 f16 (2 MB)
#define PART_OFF   2097152u    // 2 x 50000 f32 (400000 B)
#define SCORES_OFF 2500096u    // 50000 f32 (200000 B)
#define HIST_OFF   2752512u    // 65536 u32 (256 KB)
#define S_OFF      3014656u    // 65536 u32 suffix counts (256 KB)
#define META_OFF   3276800u    // [0]=T, [1]=CTOT
#define KEYS_OFF   3277312u    // 50176 u64 (401408 B)
#define SIDX_OFF   3678720u    // 5000 u32
#define SVAL_OFF   3698944u    // 5000 f32
#define AKW_OFF    3719168u    // 5000 f32
#define GPART_OFF  3739648u    // 256*2048 f32 (2 MB)
#define XF_OFF     8388608u    // 50000*2048 f16 (204.8 MB)
#define WS_NEED    213188608ull

__device__ __forceinline__ u32 mono_bits(float s){
  u32 u = __float_as_uint(s);
  return (u & 0x80000000u) ? ~u : (u | 0x80000000u);
}
__device__ __forceinline__ float inv_mono(u32 u){
  u32 b = (u & 0x80000000u) ? (u & 0x7FFFFFFFu) : ~u;
  return __uint_as_float(b);
}
__device__ __forceinline__ void gload_lds16(const void* g, void* l){
  __builtin_amdgcn_global_load_lds((__attribute__((address_space(1))) void*)(void*)g,
                                   (__attribute__((address_space(3))) void*)l, 16, 0, 0);
}

// ---------- hist clear (replaces pathological hipMemsetAsync blit) ----------
__global__ void clear_hist(u32* __restrict__ hist){
  int i = blockIdx.x * 256 + threadIdx.x;            // 64 blocks -> 16384 uint4
  ((uint4*)hist)[i] = make_uint4(0u, 0u, 0u, 0u);
}

// ---------- W1 -> fp16 ----------
__global__ void prep_w1_f16(const float* __restrict__ w1, f16* __restrict__ w1f){
  int i = (blockIdx.x * 256 + threadIdx.x) * 4;   // 1024*256*4 = 1048576 exact
  float4 v = *(const float4*)(w1 + i);
  f16x4 h;
  h[0] = (f16)v.x; h[1] = (f16)v.y; h[2] = (f16)v.z; h[3] = (f16)v.w;
  *(f16x4*)(w1f + i) = h;
}

// ---------- x -> fp16 (grid-stride, memory-bound) ----------
__global__ void prep_x_f16(const float* __restrict__ x, f16* __restrict__ xf){
  size_t i = ((size_t)blockIdx.x * 256 + threadIdx.x) * 8;
  const size_t stride = (size_t)gridDim.x * 256 * 8;
  const size_t total = (size_t)N_ROWS * D_DIM;
  for (; i < total; i += stride){
    float4 v0 = *(const float4*)(x + i);
    float4 v1 = *(const float4*)(x + i + 4);
    f16x8 h;
    h[0]=(f16)v0.x; h[1]=(f16)v0.y; h[2]=(f16)v0.z; h[3]=(f16)v0.w;
    h[4]=(f16)v1.x; h[5]=(f16)v1.y; h[6]=(f16)v1.z; h[7]=(f16)v1.w;
    *(f16x8*)(xf + i) = h;
  }
}

// ---------- 8-phase fused scores GEMM ----------
// Block 256x256, BK=64, 8 waves (2M x 4N), wave-tile 128x64. Both operands f16
// via global_load_lds (pre-swizzled source, linear LDS dest). Counted vmcnt(8).
// bx = nn&1 so the two h-halves of the same row-block are dispatch-adjacent
// (same XCD L2 chunk) -> x fetched ~once from HBM.
__global__ __launch_bounds__(512, 2) void gemm_8ph(
    const f16* __restrict__ xf, const f16* __restrict__ w1f,
    const float* __restrict__ b1, const float* __restrict__ w2, float* __restrict__ partial)
{
  __shared__ __align__(16) f16 At[2][16384];   // 256 x 64, 32 KB per buf
  __shared__ __align__(16) f16 Bt[2][16384];

  const int t = threadIdx.x, l = t & 63, w = t >> 6;
  const int wm = w >> 2, wn = w & 3;
  int nn = (blockIdx.x & 7) * 49 + (blockIdx.x >> 3);   // bijective: 392 = 8*49
  const int bx = nn & 1, by = nn >> 1;
  const int h0 = bx * 256, r0 = by * 256;

  f32x4 acc[8][4] = {};

  const int srow = t >> 3;
  const int schunk = ((t & 7) ^ (srow & 7)) * 8;       // f16 offset in row
  const f16* asrc[4];
  #pragma unroll
  for (int p = 0; p < 4; ++p){
    int gr = r0 + p * 64 + srow; if (gr > N_ROWS - 1) gr = N_ROWS - 1;
    asrc[p] = xf + (size_t)gr * D_DIM + schunk;
  }
  const f16* bsrc = w1f + (size_t)(h0 + srow) * D_DIM + schunk;
  const int dstq = srow * 64 + (t & 7) * 8;            // f16 idx; + p*4096

  int aidx[8][2], bidx[4][2];
  #pragma unroll
  for (int mt = 0; mt < 8; ++mt){
    int row = wm * 128 + mt * 16 + (l & 15);
    #pragma unroll
    for (int ks = 0; ks < 2; ++ks){
      int chunk = ks * 4 + (l >> 4);
      aidx[mt][ks] = row * 64 + ((chunk ^ (row & 7)) << 3);
    }
  }
  #pragma unroll
  for (int nt = 0; nt < 4; ++nt){
    int row = wn * 64 + nt * 16 + (l & 15);
    #pragma unroll
    for (int ks = 0; ks < 2; ++ks){
      int chunk = ks * 4 + (l >> 4);
      bidx[nt][ks] = row * 64 + ((chunk ^ (row & 7)) << 3);
    }
  }

  // prologue: stage tile 0 -> buf 0
  #pragma unroll
  for (int p = 0; p < 4; ++p)
    gload_lds16(bsrc + (size_t)p * 64 * D_DIM, &Bt[0][p * 4096 + dstq]);
  #pragma unroll
  for (int p = 0; p < 4; ++p)
    gload_lds16(asrc[p], &At[0][p * 4096 + dstq]);

  for (int kt = 0; kt < 32; ++kt){
    const int cur = kt & 1;
    const f16* Ab = At[cur];
    const f16* Bb = Bt[cur];

    if (kt + 1 < 32){
      const int k0 = (kt + 1) * 64;
      #pragma unroll
      for (int p = 0; p < 4; ++p)
        gload_lds16(bsrc + (size_t)p * 64 * D_DIM + k0, &Bt[cur ^ 1][p * 4096 + dstq]);
      #pragma unroll
      for (int p = 0; p < 4; ++p)
        gload_lds16(asrc[p] + k0, &At[cur ^ 1][p * 4096 + dstq]);
      asm volatile("s_waitcnt vmcnt(8)" ::: "memory");
    } else {
      asm volatile("s_waitcnt vmcnt(0)" ::: "memory");
    }
    __builtin_amdgcn_sched_barrier(0);
    __builtin_amdgcn_s_barrier();            // tile kt visible to all waves
    __builtin_amdgcn_sched_barrier(0);

    f16x8 bfr[4][2];
    #pragma unroll
    for (int nt = 0; nt < 4; ++nt)
      #pragma unroll
      for (int ks = 0; ks < 2; ++ks)
        bfr[nt][ks] = *(const f16x8*)&Bb[bidx[nt][ks]];

#define PHASE(m0, m1) { \
    f16x8 a00 = *(const f16x8*)&Ab[aidx[m0][0]]; \
    f16x8 a01 = *(const f16x8*)&Ab[aidx[m0][1]]; \
    f16x8 a10 = *(const f16x8*)&Ab[aidx[m1][0]]; \
    f16x8 a11 = *(const f16x8*)&Ab[aidx[m1][1]]; \
    __builtin_amdgcn_s_setprio(1); \
    _Pragma("unroll") \
    for (int nt = 0; nt < 4; ++nt){ \
      acc[m0][nt] = __builtin_amdgcn_mfma_f32_16x16x32_f16(a00, bfr[nt][0], acc[m0][nt], 0, 0, 0); \
      acc[m0][nt] = __builtin_amdgcn_mfma_f32_16x16x32_f16(a01, bfr[nt][1], acc[m0][nt], 0, 0, 0); \
      acc[m1][nt] = __builtin_amdgcn_mfma_f32_16x16x32_f16(a10, bfr[nt][0], acc[m1][nt], 0, 0, 0); \
      acc[m1][nt] = __builtin_amdgcn_mfma_f32_16x16x32_f16(a11, bfr[nt][1], acc[m1][nt], 0, 0, 0); \
    } \
    __builtin_amdgcn_s_setprio(0); \
    asm volatile("s_waitcnt lgkmcnt(0)" ::: "memory"); \
    __builtin_amdgcn_sched_barrier(0); \
    __builtin_amdgcn_s_barrier(); \
    __builtin_amdgcn_sched_barrier(0); }

    PHASE(0, 1)
    PHASE(2, 3)
    PHASE(4, 5)
    PHASE(6, 7)
#undef PHASE
  }

  // epilogue: tanh(z+b1)*w2, reduce over block's 256 cols
  float (*EPI)[4] = (float(*)[4])At;
  #pragma unroll
  for (int mt = 0; mt < 8; ++mt){
    float rsum[4] = {0.f, 0.f, 0.f, 0.f};
    #pragma unroll
    for (int nt = 0; nt < 4; ++nt){
      int h = h0 + wn * 64 + nt * 16 + (l & 15);
      float w2v = w2[h], b1v = b1[h];
      #pragma unroll
      for (int j = 0; j < 4; ++j)
        rsum[j] += tanhf(acc[mt][nt][j] + b1v) * w2v;
    }
    #pragma unroll
    for (int off = 1; off < 16; off <<= 1)
      #pragma unroll
      for (int j = 0; j < 4; ++j) rsum[j] += __shfl_xor(rsum[j], off, 64);
    if ((l & 15) == 0){
      int g = l >> 4;
      #pragma unroll
      for (int j = 0; j < 4; ++j) EPI[wm * 128 + mt * 16 + g * 4 + j][wn] = rsum[j];
    }
  }
  __syncthreads();
  if (t < 256){
    int n = r0 + t;
    if (n < N_ROWS)
      partial[(size_t)bx * N_ROWS + n] = EPI[t][0] + EPI[t][1] + EPI[t][2] + EPI[t][3];
  }
}

// ---------- fallback GEMM (R3 structure, only if ws too small) ----------
__global__ __launch_bounds__(512, 2) void gemm_fb(
    const float* __restrict__ x, const f16* __restrict__ w1f,
    const float* __restrict__ b1, const float* __restrict__ w2, float* __restrict__ partial)
{
  __shared__ __align__(16) f16 At[2][16384];
  __shared__ __align__(16) f16 Bt[2][16384];
  const int t = threadIdx.x, l = t & 63, w = t >> 6;
  const int wm = w >> 2, wn = w & 3;
  int nn = (blockIdx.x & 7) * 49 + (blockIdx.x >> 3);
  const int bx = nn & 1, by = nn >> 1;
  const int h0 = bx * 256, r0 = by * 256;
  f32x4 acc[8][4] = {};
  const int srow = t >> 3;
  const f16* wsrc = w1f + (size_t)(h0 + srow) * D_DIM + ((t & 7) ^ (srow & 7)) * 8;
  const int wdst = srow * 64 + (t & 7) * 8;
  const int xrow_l = t >> 3, xc = t & 7;
  const float* xptr[4];
  #pragma unroll
  for (int p = 0; p < 4; ++p){
    int gr = r0 + p * 64 + xrow_l; if (gr > N_ROWS - 1) gr = N_ROWS - 1;
    xptr[p] = x + (size_t)gr * D_DIM + xc * 8;
  }
  const int xdst = xrow_l * 64 + ((xc ^ (xrow_l & 7)) << 3);
  {
    #pragma unroll
    for (int p = 0; p < 4; ++p)
      gload_lds16(wsrc + (size_t)p * 64 * D_DIM, &Bt[0][p * 4096 + wdst]);
    #pragma unroll
    for (int p = 0; p < 4; ++p){
      float4 v0 = *(const float4*)(xptr[p]);
      float4 v1 = *(const float4*)(xptr[p] + 4);
      f16x8 v;
      v[0]=(f16)v0.x; v[1]=(f16)v0.y; v[2]=(f16)v0.z; v[3]=(f16)v0.w;
      v[4]=(f16)v1.x; v[5]=(f16)v1.y; v[6]=(f16)v1.z; v[7]=(f16)v1.w;
      *(f16x8*)&At[0][p * 4096 + xdst] = v;
    }
  }
  __syncthreads();
  int buf = 0;
  for (int kt = 0; kt < 32; ++kt){
    const int k0n = (kt + 1) * 64;
    float4 xr[4][2];
    if (kt < 31){
      #pragma unroll
      for (int p = 0; p < 4; ++p){
        xr[p][0] = *(const float4*)(xptr[p] + k0n);
        xr[p][1] = *(const float4*)(xptr[p] + k0n + 4);
      }
      #pragma unroll
      for (int p = 0; p < 4; ++p)
        gload_lds16(wsrc + (size_t)p * 64 * D_DIM + k0n, &Bt[buf ^ 1][p * 4096 + wdst]);
    }
    #pragma unroll
    for (int ks = 0; ks < 2; ++ks){
      const int chunk = ks * 4 + (l >> 4);
      f16x8 bfr[4];
      #pragma unroll
      for (int nt = 0; nt < 4; ++nt){
        int row = wn * 64 + nt * 16 + (l & 15);
        bfr[nt] = *(const f16x8*)&Bt[buf][row * 64 + ((chunk ^ (row & 7)) << 3)];
      }
      #pragma unroll
      for (int mt = 0; mt < 8; ++mt){
        int row = wm * 128 + mt * 16 + (l & 15);
        f16x8 af = *(const f16x8*)&At[buf][row * 64 + ((chunk ^ (row & 7)) << 3)];
        #pragma unroll
        for (int nt = 0; nt < 4; ++nt)
          acc[mt][nt] = __builtin_amdgcn_mfma_f32_16x16x32_f16(af, bfr[nt], acc[mt][nt], 0, 0, 0);
      }
    }
    if (kt < 31){
      #pragma unroll
      for (int p = 0; p < 4; ++p){
        f16x8 v;
        v[0]=(f16)xr[p][0].x; v[1]=(f16)xr[p][0].y; v[2]=(f16)xr[p][0].z; v[3]=(f16)xr[p][0].w;
        v[4]=(f16)xr[p][1].x; v[5]=(f16)xr[p][1].y; v[6]=(f16)xr[p][1].z; v[7]=(f16)xr[p][1].w;
        *(f16x8*)&At[buf ^ 1][p * 4096 + xdst] = v;
      }
    }
    __syncthreads();
    buf ^= 1;
  }
  float (*EPI)[4] = (float(*)[4])At;
  #pragma unroll
  for (int mt = 0; mt < 8; ++mt){
    float rsum[4] = {0.f, 0.f, 0.f, 0.f};
    #pragma unroll
    for (int nt = 0; nt < 4; ++nt){
      int h = h0 + wn * 64 + nt * 16 + (l & 15);
      float w2v = w2[h], b1v = b1[h];
      #pragma unroll
      for (int j = 0; j < 4; ++j)
        rsum[j] += tanhf(acc[mt][nt][j] + b1v) * w2v;
    }
    #pragma unroll
    for (int off = 1; off < 16; off <<= 1)
      #pragma unroll
      for (int j = 0; j < 4; ++j) rsum[j] += __shfl_xor(rsum[j], off, 64);
    if ((l & 15) == 0){
      int g = l >> 4;
      #pragma unroll
      for (int j = 0; j < 4; ++j) EPI[wm * 128 + mt * 16 + g * 4 + j][wn] = rsum[j];
    }
  }
  __syncthreads();
  if (t < 256){
    int n = r0 + t;
    if (n < N_ROWS)
      partial[(size_t)bx * N_ROWS + n] = EPI[t][0] + EPI[t][1] + EPI[t][2] + EPI[t][3];
  }
}

// ---------- score reduce + 16-bit-bin histogram ----------
__global__ void reduce_hist(const float* __restrict__ partial, float* __restrict__ scores,
                            u32* __restrict__ hist){
  int n = blockIdx.x * 256 + threadIdx.x;
  if (n >= N_ROWS) return;
  float s = partial[n] + partial[N_ROWS + n];     // b2 omitted: cancels in softmax/top-k
  scores[n] = s;
  atomicAdd(&hist[mono_bits(s) >> 16], 1u);
}

// ---------- suffix scan: S[b] = #elems in bins > b; find threshold bin T ----------
__global__ __launch_bounds__(1024) void scan_S(const u32* __restrict__ hist,
                                               u32* __restrict__ S, u32* __restrict__ meta){
  __shared__ u32 csum[1024];
  const int t = threadIdx.x;
  u32 sum = 0;
  #pragma unroll 4
  for (int i = 0; i < 64; ++i) sum += hist[t * 64 + i];
  csum[t] = sum;
  __syncthreads();
  // suffix scan: csum[t] = sum over t' >= t
  for (int off = 1; off < 1024; off <<= 1){
    u32 v = (t + off < 1024) ? csum[t + off] : 0u;
    __syncthreads();
    csum[t] += v;
    __syncthreads();
  }
  u32 running = (t < 1023) ? csum[t + 1] : 0u;    // elems in bins >= (t+1)*64
  for (int i = 63; i >= 0; --i){
    int b = t * 64 + i;
    u32 h = hist[b];
    S[b] = running;                                // count of bins > b
    if (running < (u32)KSEL && running + h >= (u32)KSEL){
      meta[0] = (u32)b;                            // threshold bin
      meta[1] = running + h;                       // CTOT = count of bins >= T
    }
    running += h;
  }
}

// ---------- scatter candidates to their bin segment ----------
__global__ void scatter_cand(const float* __restrict__ scores, u32* __restrict__ hist,
                             const u32* __restrict__ S, const u32* __restrict__ meta,
                             u64* __restrict__ keys){
  int n = blockIdx.x * 256 + threadIdx.x;
  if (n >= N_ROWS) return;
  u32 u = mono_bits(scores[n]);
  u32 b = u >> 16;
  if (b >= meta[0]){
    u32 rank = atomicSub(&hist[b], 1u) - 1u;       // arbitrary within-bin order
    u32 pos = S[b] + rank;
    keys[pos] = ((u64)u << 32) | (u32)(~n);        // value desc, index asc
  }
}

// ---------- rank-fix within bin segments + emit exact sorted top-k ----------
__global__ void emit_topk(const u64* __restrict__ keys, const u32* __restrict__ S,
                          const u32* __restrict__ meta,
                          u32* __restrict__ sidx, float* __restrict__ svals){
  u32 p = blockIdx.x * 256 + threadIdx.x;
  u32 CTOT = meta[1];
  if (p >= CTOT) return;
  u64 key = keys[p];
  u32 b = (u32)(key >> 48);
  u32 lo = S[b];
  u32 hi = (b > 0) ? S[b - 1] : CTOT;              // S[b-1] = count of bins >= b
  u32 c = 0;
  for (u32 q = lo; q < hi; ++q) c += (keys[q] > key);
  u32 r = lo + c;
  if (r < (u32)KSEL){
    sidx[r] = ~(u32)(key & 0xFFFFFFFFull);
    svals[r] = inv_mono((u32)(key >> 32));
  }
}

// ---------- softmax over top-k (global Z and b2 cancel; renormalize) ----------
__global__ __launch_bounds__(1024) void softmax_topk(
    const float* __restrict__ svals, float* __restrict__ akw, float* __restrict__ out)
{
  __shared__ float red[1024];
  const int t = threadIdx.x;
  float m = svals[0];                               // rank 0 = max score
  float ev[5];
  float local = 0.f;
  #pragma unroll
  for (int r = 0; r < 5; ++r){
    int j = t + r * 1024;
    if (j < KSEL){ ev[r] = expf(svals[j] - m); local += ev[r]; }
  }
  red[t] = local;
  __syncthreads();
  for (int o = 512; o > 0; o >>= 1){ if (t < o) red[t] += red[t + o]; __syncthreads(); }
  float Ssum = red[0];
  #pragma unroll
  for (int r = 0; r < 5; ++r){
    int j = t + r * 1024;
    if (j < KSEL){
      float a = ev[r] / Ssum;
      akw[j] = a; out[D_DIM + j] = a;
    }
  }
}

// ---------- gather + weighted sum (deterministic 2-pass) ----------
__global__ void gather_M(const float* __restrict__ x, const u32* __restrict__ sidx,
                         const float* __restrict__ akw, float* __restrict__ gpart){
  int t = threadIdx.x, b = blockIdx.x;   // 256 blocks
  float a8[8] = {0.f,0.f,0.f,0.f,0.f,0.f,0.f,0.f};
  for (int j = b; j < KSEL; j += 256){
    float a = akw[j];
    const float* xr = x + (size_t)sidx[j] * D_DIM;
    #pragma unroll
    for (int c = 0; c < 8; ++c) a8[c] += a * xr[t + c * 256];
  }
  #pragma unroll
  for (int c = 0; c < 8; ++c) gpart[(size_t)b * D_DIM + t + c * 256] = a8[c];
}
__global__ void reduce_M(const float* __restrict__ gpart, float* __restrict__ out){
  int d = blockIdx.x * 256 + threadIdx.x;
  float s = 0.f;
  for (int b = 0; b < 256; ++b) s += gpart[(size_t)b * D_DIM + d];
  out[d] = s;
}

extern "C" void kernel_launch(void* const* d_in, const int* in_sizes, int n_in,
                              void* d_out, int out_size, void* d_ws, size_t ws_size,
                              hipStream_t stream) {
  const float* x  = (const float*)d_in[0];
  const float* W1 = (const float*)d_in[1];
  const float* b1 = (const float*)d_in[2];
  const float* W2 = (const float*)d_in[3];
  // b2 (d_in[4]) cancels in softmax/top-k -> unused
  float* out = (float*)d_out;
  char* ws = (char*)d_ws;

  f16* w1f     = (f16*)(ws + W1F_OFF);
  float* part  = (float*)(ws + PART_OFF);
  float* scr   = (float*)(ws + SCORES_OFF);
  u32* hist    = (u32*)(ws + HIST_OFF);
  u32* Sarr    = (u32*)(ws + S_OFF);
  u32* meta    = (u32*)(ws + META_OFF);
  u64* keys    = (u64*)(ws + KEYS_OFF);
  u32* sidx    = (u32*)(ws + SIDX_OFF);
  float* svals = (float*)(ws + SVAL_OFF);
  float* akw   = (float*)(ws + AKW_OFF);
  float* gpart = (float*)(ws + GPART_OFF);
  f16* xf      = (f16*)(ws + XF_OFF);

  (void)in_sizes; (void)n_in; (void)out_size;

  clear_hist<<<64, 256, 0, stream>>>(hist);
  prep_w1_f16<<<1024, 256, 0, stream>>>(W1, w1f);
  if (ws_size >= WS_NEED){
    prep_x_f16<<<2048, 256, 0, stream>>>(x, xf);
    gemm_8ph<<<392, 512, 0, stream>>>(xf, w1f, b1, W2, part);
  } else {
    gemm_fb<<<392, 512, 0, stream>>>(x, w1f, b1, W2, part);
  }
  reduce_hist<<<196, 256, 0, stream>>>(part, scr, hist);
  scan_S<<<1, 1024, 0, stream>>>(hist, Sarr, meta);
  scatter_cand<<<196, 256, 0, stream>>>(scr, hist, Sarr, meta, keys);
  emit_topk<<<196, 256, 0, stream>>>(keys, Sarr, meta, sidx, svals);
  softmax_topk<<<1, 1024, 0, stream>>>(svals, akw, out);
  gather_M<<<256, 256, 0, stream>>>(x, sidx, akw, gpart);
  reduce_M<<<8, 256, 0, stream>>>(gpart, out);
}

// Round 6
// 455.248 us; speedup vs baseline: 1.0839x; 1.0432x over previous
//
#include <hip/hip_runtime.h>

typedef unsigned short u16;
typedef unsigned int   u32;
typedef unsigned long long u64;
typedef _Float16 f16;
typedef f16 f16x8 __attribute__((ext_vector_type(8)));
typedef f16 f16x4 __attribute__((ext_vector_type(4)));
typedef float f32x4 __attribute__((ext_vector_type(4)));

#define N_ROWS 50000
#define D_DIM  2048
#define H_DIM  512
#define KSEL   5000
#define NBIN   65536

// ---------- workspace layout (bytes) ----------
#define W1F_OFF    0u          // 512*2048 f16 (2 MB)
#define PART_OFF   2097152u    // 2 x 50000 f32 (400000 B)
#define SCORES_OFF 2500096u    // 50000 f32 (200000 B)
#define HIST_OFF   2752512u    // 65536 u32 (256 KB)
#define S_OFF      3014656u    // 65536 u32 suffix counts (256 KB)
#define META_OFF   3276800u    // [0]=T, [1]=CTOT
#define KEYS_OFF   3277312u    // 50176 u64 (401408 B)
#define SIDX_OFF   3678720u    // 5000 u32
#define SVAL_OFF   3698944u    // 5000 f32
#define AKW_OFF    3719168u    // 5000 f32
#define GPART_OFF  3739648u    // 256*2048 f32 (2 MB)
#define XF_OFF     8388608u    // 50000*2048 f16 (204.8 MB)
#define WS_NEED    213188608ull

__device__ __forceinline__ u32 mono_bits(float s){
  u32 u = __float_as_uint(s);
  return (u & 0x80000000u) ? ~u : (u | 0x80000000u);
}
__device__ __forceinline__ float inv_mono(u32 u){
  u32 b = (u & 0x80000000u) ? (u & 0x7FFFFFFFu) : ~u;
  return __uint_as_float(b);
}
__device__ __forceinline__ void gload_lds16(const void* g, void* l){
  __builtin_amdgcn_global_load_lds((__attribute__((address_space(1))) void*)(void*)g,
                                   (__attribute__((address_space(3))) void*)l, 16, 0, 0);
}

// ---------- hist clear ----------
__global__ void clear_hist(u32* __restrict__ hist){
  int i = blockIdx.x * 256 + threadIdx.x;            // 64 blocks -> 16384 uint4
  ((uint4*)hist)[i] = make_uint4(0u, 0u, 0u, 0u);
}

// ---------- W1 -> fp16 ----------
__global__ void prep_w1_f16(const float* __restrict__ w1, f16* __restrict__ w1f){
  int i = (blockIdx.x * 256 + threadIdx.x) * 4;   // 1024*256*4 = 1048576 exact
  float4 v = *(const float4*)(w1 + i);
  f16x4 h;
  h[0] = (f16)v.x; h[1] = (f16)v.y; h[2] = (f16)v.z; h[3] = (f16)v.w;
  *(f16x4*)(w1f + i) = h;
}

// ---------- x -> fp16 (grid-stride, memory-bound) ----------
__global__ void prep_x_f16(const float* __restrict__ x, f16* __restrict__ xf){
  size_t i = ((size_t)blockIdx.x * 256 + threadIdx.x) * 8;
  const size_t stride = (size_t)gridDim.x * 256 * 8;
  const size_t total = (size_t)N_ROWS * D_DIM;
  for (; i < total; i += stride){
    float4 v0 = *(const float4*)(x + i);
    float4 v1 = *(const float4*)(x + i + 4);
    f16x8 h;
    h[0]=(f16)v0.x; h[1]=(f16)v0.y; h[2]=(f16)v0.z; h[3]=(f16)v0.w;
    h[4]=(f16)v1.x; h[5]=(f16)v1.y; h[6]=(f16)v1.z; h[7]=(f16)v1.w;
    *(f16x8*)(xf + i) = h;
  }
}

// ---------- 2-phase fused scores GEMM ----------
// Block 256x256, BK=64, 8 waves (2M x 4N), wave-tile 128x64. Both operands f16
// via global_load_lds (pre-swizzled source, linear LDS dest). Counted vmcnt(8):
// next tile's 8 DMAs stay in flight across the barrier. ONE compute phase per
// K-tile (compiler schedules lgkmcnt interleave); 2 barriers/tile total.
__global__ __launch_bounds__(512, 2) void gemm_2ph(
    const f16* __restrict__ xf, const f16* __restrict__ w1f,
    const float* __restrict__ b1, const float* __restrict__ w2, float* __restrict__ partial)
{
  __shared__ __align__(16) f16 At[2][16384];   // 256 x 64, 32 KB per buf
  __shared__ __align__(16) f16 Bt[2][16384];

  const int t = threadIdx.x, l = t & 63, w = t >> 6;
  const int wm = w >> 2, wn = w & 3;
  int nn = (blockIdx.x & 7) * 49 + (blockIdx.x >> 3);   // bijective: 392 = 8*49
  const int bx = nn & 1, by = nn >> 1;                   // pair (2j,2j+1): same rows, both h-halves
  const int h0 = bx * 256, r0 = by * 256;

  f32x4 acc[8][4] = {};

  const int srow = t >> 3;
  const int schunk = ((t & 7) ^ (srow & 7)) * 8;       // f16 offset in row (pre-swizzled source)
  const f16* asrc[4];
  #pragma unroll
  for (int p = 0; p < 4; ++p){
    int gr = r0 + p * 64 + srow; if (gr > N_ROWS - 1) gr = N_ROWS - 1;
    asrc[p] = xf + (size_t)gr * D_DIM + schunk;
  }
  const f16* bsrc = w1f + (size_t)(h0 + srow) * D_DIM + schunk;
  const int dstq = srow * 64 + (t & 7) * 8;            // f16 idx; + p*4096

  // prologue: stage tile 0 -> buf 0
  #pragma unroll
  for (int p = 0; p < 4; ++p)
    gload_lds16(bsrc + (size_t)p * 64 * D_DIM, &Bt[0][p * 4096 + dstq]);
  #pragma unroll
  for (int p = 0; p < 4; ++p)
    gload_lds16(asrc[p], &At[0][p * 4096 + dstq]);

  for (int kt = 0; kt < 32; ++kt){
    const int cur = kt & 1;
    const f16* Ab = At[cur];
    const f16* Bb = Bt[cur];

    // issue next tile's DMAs (WAR-safe: buf cur^1 readers retired at end of kt-1)
    if (kt + 1 < 32){
      const int k0 = (kt + 1) * 64;
      #pragma unroll
      for (int p = 0; p < 4; ++p)
        gload_lds16(bsrc + (size_t)p * 64 * D_DIM + k0, &Bt[cur ^ 1][p * 4096 + dstq]);
      #pragma unroll
      for (int p = 0; p < 4; ++p)
        gload_lds16(asrc[p] + k0, &At[cur ^ 1][p * 4096 + dstq]);
      asm volatile("s_waitcnt vmcnt(8)" ::: "memory");   // tile kt landed; kt+1 in flight
    } else {
      asm volatile("s_waitcnt vmcnt(0)" ::: "memory");
    }
    __builtin_amdgcn_sched_barrier(0);
    __builtin_amdgcn_s_barrier();            // tile kt visible to all waves
    __builtin_amdgcn_sched_barrier(0);

    // single compute phase: compiler interleaves ds_read/lgkmcnt/MFMA
    __builtin_amdgcn_s_setprio(1);
    #pragma unroll
    for (int ks = 0; ks < 2; ++ks){
      const int chunk = ks * 4 + (l >> 4);
      f16x8 bfr[4];
      #pragma unroll
      for (int nt = 0; nt < 4; ++nt){
        int row = wn * 64 + nt * 16 + (l & 15);
        bfr[nt] = *(const f16x8*)&Bb[row * 64 + ((chunk ^ (row & 7)) << 3)];
      }
      #pragma unroll
      for (int mt = 0; mt < 8; ++mt){
        int row = wm * 128 + mt * 16 + (l & 15);
        f16x8 af = *(const f16x8*)&Ab[row * 64 + ((chunk ^ (row & 7)) << 3)];
        #pragma unroll
        for (int nt = 0; nt < 4; ++nt)
          acc[mt][nt] = __builtin_amdgcn_mfma_f32_16x16x32_f16(af, bfr[nt], acc[mt][nt], 0, 0, 0);
      }
    }
    __builtin_amdgcn_s_setprio(0);

    asm volatile("s_waitcnt lgkmcnt(0)" ::: "memory");   // all reads of buf cur retired
    __builtin_amdgcn_sched_barrier(0);
    __builtin_amdgcn_s_barrier();
    __builtin_amdgcn_sched_barrier(0);
  }

  // epilogue: tanh(z+b1)*w2, reduce over block's 256 cols
  // acc[mt][nt] reg j: row = wm*128 + mt*16 + (l>>4)*4 + j, col = wn*64 + nt*16 + (l&15)
  float (*EPI)[4] = (float(*)[4])At;
  #pragma unroll
  for (int mt = 0; mt < 8; ++mt){
    float rsum[4] = {0.f, 0.f, 0.f, 0.f};
    #pragma unroll
    for (int nt = 0; nt < 4; ++nt){
      int h = h0 + wn * 64 + nt * 16 + (l & 15);
      float w2v = w2[h], b1v = b1[h];
      #pragma unroll
      for (int j = 0; j < 4; ++j)
        rsum[j] += tanhf(acc[mt][nt][j] + b1v) * w2v;
    }
    #pragma unroll
    for (int off = 1; off < 16; off <<= 1)
      #pragma unroll
      for (int j = 0; j < 4; ++j) rsum[j] += __shfl_xor(rsum[j], off, 64);
    if ((l & 15) == 0){
      int g = l >> 4;
      #pragma unroll
      for (int j = 0; j < 4; ++j) EPI[wm * 128 + mt * 16 + g * 4 + j][wn] = rsum[j];
    }
  }
  __syncthreads();
  if (t < 256){
    int n = r0 + t;
    if (n < N_ROWS)
      partial[(size_t)bx * N_ROWS + n] = EPI[t][0] + EPI[t][1] + EPI[t][2] + EPI[t][3];
  }
}

// ---------- fallback GEMM (reg-staged x, only if ws too small) ----------
__global__ __launch_bounds__(512, 2) void gemm_fb(
    const float* __restrict__ x, const f16* __restrict__ w1f,
    const float* __restrict__ b1, const float* __restrict__ w2, float* __restrict__ partial)
{
  __shared__ __align__(16) f16 At[2][16384];
  __shared__ __align__(16) f16 Bt[2][16384];
  const int t = threadIdx.x, l = t & 63, w = t >> 6;
  const int wm = w >> 2, wn = w & 3;
  int nn = (blockIdx.x & 7) * 49 + (blockIdx.x >> 3);
  const int bx = nn & 1, by = nn >> 1;
  const int h0 = bx * 256, r0 = by * 256;
  f32x4 acc[8][4] = {};
  const int srow = t >> 3;
  const f16* wsrc = w1f + (size_t)(h0 + srow) * D_DIM + ((t & 7) ^ (srow & 7)) * 8;
  const int wdst = srow * 64 + (t & 7) * 8;
  const int xrow_l = t >> 3, xc = t & 7;
  const float* xptr[4];
  #pragma unroll
  for (int p = 0; p < 4; ++p){
    int gr = r0 + p * 64 + xrow_l; if (gr > N_ROWS - 1) gr = N_ROWS - 1;
    xptr[p] = x + (size_t)gr * D_DIM + xc * 8;
  }
  const int xdst = xrow_l * 64 + ((xc ^ (xrow_l & 7)) << 3);
  {
    #pragma unroll
    for (int p = 0; p < 4; ++p)
      gload_lds16(wsrc + (size_t)p * 64 * D_DIM, &Bt[0][p * 4096 + wdst]);
    #pragma unroll
    for (int p = 0; p < 4; ++p){
      float4 v0 = *(const float4*)(xptr[p]);
      float4 v1 = *(const float4*)(xptr[p] + 4);
      f16x8 v;
      v[0]=(f16)v0.x; v[1]=(f16)v0.y; v[2]=(f16)v0.z; v[3]=(f16)v0.w;
      v[4]=(f16)v1.x; v[5]=(f16)v1.y; v[6]=(f16)v1.z; v[7]=(f16)v1.w;
      *(f16x8*)&At[0][p * 4096 + xdst] = v;
    }
  }
  __syncthreads();
  int buf = 0;
  for (int kt = 0; kt < 32; ++kt){
    const int k0n = (kt + 1) * 64;
    float4 xr[4][2];
    if (kt < 31){
      #pragma unroll
      for (int p = 0; p < 4; ++p){
        xr[p][0] = *(const float4*)(xptr[p] + k0n);
        xr[p][1] = *(const float4*)(xptr[p] + k0n + 4);
      }
      #pragma unroll
      for (int p = 0; p < 4; ++p)
        gload_lds16(wsrc + (size_t)p * 64 * D_DIM + k0n, &Bt[buf ^ 1][p * 4096 + wdst]);
    }
    #pragma unroll
    for (int ks = 0; ks < 2; ++ks){
      const int chunk = ks * 4 + (l >> 4);
      f16x8 bfr[4];
      #pragma unroll
      for (int nt = 0; nt < 4; ++nt){
        int row = wn * 64 + nt * 16 + (l & 15);
        bfr[nt] = *(const f16x8*)&Bt[buf][row * 64 + ((chunk ^ (row & 7)) << 3)];
      }
      #pragma unroll
      for (int mt = 0; mt < 8; ++mt){
        int row = wm * 128 + mt * 16 + (l & 15);
        f16x8 af = *(const f16x8*)&At[buf][row * 64 + ((chunk ^ (row & 7)) << 3)];
        #pragma unroll
        for (int nt = 0; nt < 4; ++nt)
          acc[mt][nt] = __builtin_amdgcn_mfma_f32_16x16x32_f16(af, bfr[nt], acc[mt][nt], 0, 0, 0);
      }
    }
    if (kt < 31){
      #pragma unroll
      for (int p = 0; p < 4; ++p){
        f16x8 v;
        v[0]=(f16)xr[p][0].x; v[1]=(f16)xr[p][0].y; v[2]=(f16)xr[p][0].z; v[3]=(f16)xr[p][0].w;
        v[4]=(f16)xr[p][1].x; v[5]=(f16)xr[p][1].y; v[6]=(f16)xr[p][1].z; v[7]=(f16)xr[p][1].w;
        *(f16x8*)&At[buf ^ 1][p * 4096 + xdst] = v;
      }
    }
    __syncthreads();
    buf ^= 1;
  }
  float (*EPI)[4] = (float(*)[4])At;
  #pragma unroll
  for (int mt = 0; mt < 8; ++mt){
    float rsum[4] = {0.f, 0.f, 0.f, 0.f};
    #pragma unroll
    for (int nt = 0; nt < 4; ++nt){
      int h = h0 + wn * 64 + nt * 16 + (l & 15);
      float w2v = w2[h], b1v = b1[h];
      #pragma unroll
      for (int j = 0; j < 4; ++j)
        rsum[j] += tanhf(acc[mt][nt][j] + b1v) * w2v;
    }
    #pragma unroll
    for (int off = 1; off < 16; off <<= 1)
      #pragma unroll
      for (int j = 0; j < 4; ++j) rsum[j] += __shfl_xor(rsum[j], off, 64);
    if ((l & 15) == 0){
      int g = l >> 4;
      #pragma unroll
      for (int j = 0; j < 4; ++j) EPI[wm * 128 + mt * 16 + g * 4 + j][wn] = rsum[j];
    }
  }
  __syncthreads();
  if (t < 256){
    int n = r0 + t;
    if (n < N_ROWS)
      partial[(size_t)bx * N_ROWS + n] = EPI[t][0] + EPI[t][1] + EPI[t][2] + EPI[t][3];
  }
}

// ---------- score reduce + 16-bit-bin histogram ----------
__global__ void reduce_hist(const float* __restrict__ partial, float* __restrict__ scores,
                            u32* __restrict__ hist){
  int n = blockIdx.x * 256 + threadIdx.x;
  if (n >= N_ROWS) return;
  float s = partial[n] + partial[N_ROWS + n];     // b2 omitted: cancels in softmax/top-k
  scores[n] = s;
  atomicAdd(&hist[mono_bits(s) >> 16], 1u);
}

// ---------- suffix scan: S[b] = #elems in bins > b; find threshold bin T ----------
__global__ __launch_bounds__(1024) void scan_S(const u32* __restrict__ hist,
                                               u32* __restrict__ S, u32* __restrict__ meta){
  __shared__ u32 csum[1024];
  const int t = threadIdx.x;
  u32 sum = 0;
  #pragma unroll 4
  for (int i = 0; i < 64; ++i) sum += hist[t * 64 + i];
  csum[t] = sum;
  __syncthreads();
  for (int off = 1; off < 1024; off <<= 1){
    u32 v = (t + off < 1024) ? csum[t + off] : 0u;
    __syncthreads();
    csum[t] += v;
    __syncthreads();
  }
  u32 running = (t < 1023) ? csum[t + 1] : 0u;    // elems in bins >= (t+1)*64
  for (int i = 63; i >= 0; --i){
    int b = t * 64 + i;
    u32 h = hist[b];
    S[b] = running;                                // count of bins > b
    if (running < (u32)KSEL && running + h >= (u32)KSEL){
      meta[0] = (u32)b;                            // threshold bin
      meta[1] = running + h;                       // CTOT
    }
    running += h;
  }
}

// ---------- scatter candidates to their bin segment ----------
__global__ void scatter_cand(const float* __restrict__ scores, u32* __restrict__ hist,
                             const u32* __restrict__ S, const u32* __restrict__ meta,
                             u64* __restrict__ keys){
  int n = blockIdx.x * 256 + threadIdx.x;
  if (n >= N_ROWS) return;
  u32 u = mono_bits(scores[n]);
  u32 b = u >> 16;
  if (b >= meta[0]){
    u32 rank = atomicSub(&hist[b], 1u) - 1u;
    u32 pos = S[b] + rank;
    keys[pos] = ((u64)u << 32) | (u32)(~n);        // value desc, index asc
  }
}

// ---------- rank-fix within bin segments + emit exact sorted top-k ----------
__global__ void emit_topk(const u64* __restrict__ keys, const u32* __restrict__ S,
                          const u32* __restrict__ meta,
                          u32* __restrict__ sidx, float* __restrict__ svals){
  u32 p = blockIdx.x * 256 + threadIdx.x;
  u32 CTOT = meta[1];
  if (p >= CTOT) return;
  u64 key = keys[p];
  u32 b = (u32)(key >> 48);
  u32 lo = S[b];
  u32 hi = (b > 0) ? S[b - 1] : CTOT;
  u32 c = 0;
  for (u32 q = lo; q < hi; ++q) c += (keys[q] > key);
  u32 r = lo + c;
  if (r < (u32)KSEL){
    sidx[r] = ~(u32)(key & 0xFFFFFFFFull);
    svals[r] = inv_mono((u32)(key >> 32));
  }
}

// ---------- softmax over top-k (global Z and b2 cancel; renormalize) ----------
__global__ __launch_bounds__(1024) void softmax_topk(
    const float* __restrict__ svals, float* __restrict__ akw, float* __restrict__ out)
{
  __shared__ float red[1024];
  const int t = threadIdx.x;
  float m = svals[0];
  float ev[5];
  float local = 0.f;
  #pragma unroll
  for (int r = 0; r < 5; ++r){
    int j = t + r * 1024;
    if (j < KSEL){ ev[r] = expf(svals[j] - m); local += ev[r]; }
  }
  red[t] = local;
  __syncthreads();
  for (int o = 512; o > 0; o >>= 1){ if (t < o) red[t] += red[t + o]; __syncthreads(); }
  float Ssum = red[0];
  #pragma unroll
  for (int r = 0; r < 5; ++r){
    int j = t + r * 1024;
    if (j < KSEL){
      float a = ev[r] / Ssum;
      akw[j] = a; out[D_DIM + j] = a;
    }
  }
}

// ---------- gather + weighted sum (deterministic 2-pass) ----------
__global__ void gather_M(const float* __restrict__ x, const u32* __restrict__ sidx,
                         const float* __restrict__ akw, float* __restrict__ gpart){
  int t = threadIdx.x, b = blockIdx.x;   // 256 blocks
  float a8[8] = {0.f,0.f,0.f,0.f,0.f,0.f,0.f,0.f};
  for (int j = b; j < KSEL; j += 256){
    float a = akw[j];
    const float* xr = x + (size_t)sidx[j] * D_DIM;
    #pragma unroll
    for (int c = 0; c < 8; ++c) a8[c] += a * xr[t + c * 256];
  }
  #pragma unroll
  for (int c = 0; c < 8; ++c) gpart[(size_t)b * D_DIM + t + c * 256] = a8[c];
}
__global__ void reduce_M(const float* __restrict__ gpart, float* __restrict__ out){
  int d = blockIdx.x * 256 + threadIdx.x;
  float s = 0.f;
  for (int b = 0; b < 256; ++b) s += gpart[(size_t)b * D_DIM + d];
  out[d] = s;
}

extern "C" void kernel_launch(void* const* d_in, const int* in_sizes, int n_in,
                              void* d_out, int out_size, void* d_ws, size_t ws_size,
                              hipStream_t stream) {
  const float* x  = (const float*)d_in[0];
  const float* W1 = (const float*)d_in[1];
  const float* b1 = (const float*)d_in[2];
  const float* W2 = (const float*)d_in[3];
  // b2 (d_in[4]) cancels in softmax/top-k -> unused
  float* out = (float*)d_out;
  char* ws = (char*)d_ws;

  f16* w1f     = (f16*)(ws + W1F_OFF);
  float* part  = (float*)(ws + PART_OFF);
  float* scr   = (float*)(ws + SCORES_OFF);
  u32* hist    = (u32*)(ws + HIST_OFF);
  u32* Sarr    = (u32*)(ws + S_OFF);
  u32* meta    = (u32*)(ws + META_OFF);
  u64* keys    = (u64*)(ws + KEYS_OFF);
  u32* sidx    = (u32*)(ws + SIDX_OFF);
  float* svals = (float*)(ws + SVAL_OFF);
  float* akw   = (float*)(ws + AKW_OFF);
  float* gpart = (float*)(ws + GPART_OFF);
  f16* xf      = (f16*)(ws + XF_OFF);

  (void)in_sizes; (void)n_in; (void)out_size;

  clear_hist<<<64, 256, 0, stream>>>(hist);
  prep_w1_f16<<<1024, 256, 0, stream>>>(W1, w1f);
  if (ws_size >= WS_NEED){
    prep_x_f16<<<2048, 256, 0, stream>>>(x, xf);
    gemm_2ph<<<392, 512, 0, stream>>>(xf, w1f, b1, W2, part);
  } else {
    gemm_fb<<<392, 512, 0, stream>>>(x, w1f, b1, W2, part);
  }
  reduce_hist<<<196, 256, 0, stream>>>(part, scr, hist);
  scan_S<<<1, 1024, 0, stream>>>(hist, Sarr, meta);
  scatter_cand<<<196, 256, 0, stream>>>(scr, hist, Sarr, meta, keys);
  emit_topk<<<196, 256, 0, stream>>>(keys, Sarr, meta, sidx, svals);
  softmax_topk<<<1, 1024, 0, stream>>>(svals, akw, out);
  gather_M<<<256, 256, 0, stream>>>(x, sidx, akw, gpart);
  reduce_M<<<8, 256, 0, stream>>>(gpart, out);
}